// Round 3
// baseline (543.999 us; speedup 1.0000x reference)
//
#include <hip/hip_runtime.h>
#include <hip/hip_bf16.h>

#define N_NODE 50000
#define N_EDGE 625000
#define FDIM 128
#define CAP 64        // bucket capacity per node (max in-degree ~35 for Poisson(12.5))

typedef __bf16 bf16x8 __attribute__((ext_vector_type(8)));
typedef float floatx4 __attribute__((ext_vector_type(4)));

#define MT 64        // nodes per block
#define XS_LD 264    // x-tile row stride (bf16): 256 + 8 pad (row = 528 B, 16B-aligned)
#define H_LD 136     // h row stride (bf16): 128 + 8 pad

__device__ inline bf16x8 as_bf16x8(uint4 v) {
    union { uint4 u; bf16x8 b; } c; c.u = v; return c.b;
}

// ---------------- W repack + count zero (fused) ----------------
// blocks 0..31: Wpack[tile][nt][lane] = uint4 of 8 bf16: W[k0+(lane>>4)*8+j][nt*16+(lane&15)]
//   tiles: 0..7 = W1 (K=256), 8..11 = W2, 12..15 = W3
// blocks 32..63: zero count[]
__global__ __launch_bounds__(256) void wrepack_kernel(
    const float* __restrict__ W1, const float* __restrict__ W2,
    const float* __restrict__ W3, uint4* __restrict__ wp,
    int* __restrict__ count)
{
    if (blockIdx.x >= 32) {
        int idx = (blockIdx.x - 32) * 256 + threadIdx.x;
        for (int i = idx; i < N_NODE; i += 32 * 256) count[i] = 0;
        return;
    }
    int g = blockIdx.x * 256 + threadIdx.x;   // 0..8191
    int lane = g & 63;
    int nt = (g >> 6) & 7;
    int tile = g >> 9;
    const float* W; int k0;
    if (tile < 8)       { W = W1; k0 = tile * 32; }
    else if (tile < 12) { W = W2; k0 = (tile - 8) * 32; }
    else                { W = W3; k0 = (tile - 12) * 32; }
    int n = nt * 16 + (lane & 15);
    int kb = k0 + (lane >> 4) * 8;
    union { __bf16 b[8]; uint4 u; } p;
#pragma unroll
    for (int j = 0; j < 8; ++j) p.b[j] = (__bf16)W[(kb + j) * 128 + n];
    wp[g] = p.u;
}

// ---------------- bucket scatter ----------------
__global__ __launch_bounds__(256) void scatter_kernel(
    const int* __restrict__ recv, int* __restrict__ count, int* __restrict__ eid)
{
    int e = blockIdx.x * 256 + threadIdx.x;
    if (e < N_EDGE) {
        int r = recv[e];
        int p = atomicAdd(&count[r], 1);
        if (p < CAP) eid[(r << 6) + p] = e;
    }
}

// ------------- fused gather + MLP + LayerNorm + residual -------------
// LDS plan (34944 B -> 4 blocks/CU):
//   xs = smem[0..16896)           x-tile, alive through GEMM1
//   h1 = smem[0..8704)            written after sync (xs dead), read by GEMM2
//   h2 = smem[8704..17408)        disjoint from h1; written by epi2, read by GEMM3
__global__ __launch_bounds__(256, 4) void mlp_kernel(
    const float* __restrict__ nodef, const float4* __restrict__ ef4,
    const int* __restrict__ count, const int* __restrict__ eid,
    const uint4* __restrict__ wp,
    const float* __restrict__ b1, const float* __restrict__ b2,
    const float* __restrict__ b3,
    const float* __restrict__ gamma, const float* __restrict__ beta,
    float* __restrict__ out)
{
    __shared__ __bf16 smem[17472];
    __bf16* xs = smem;
    __bf16* h1 = smem;
    __bf16* h2 = smem + 8704;

    const int t = threadIdx.x;
    const int wave = t >> 6;
    const int lane = t & 63;
    const int quad = lane >> 4;
    const int l16 = lane & 15;
    const int w16 = wave << 4;
    const int q8 = quad << 3;
    const int node0 = blockIdx.x * MT;

    // ---- stage node features into xs cols 0..127 ----
    const float4* nf4 = (const float4*)nodef;
#pragma unroll
    for (int i = 0; i < 8; ++i) {
        int it = i * 256 + t;
        int row = it >> 5;
        int c4 = it & 31;
        int node = node0 + row;
        if (node >= N_NODE) node = N_NODE - 1;   // junk ok; masked at store
        float4 v = nf4[(long)node * 32 + c4];
        union { __bf16 b[4]; short4 s; } u;
        u.b[0] = (__bf16)v.x; u.b[1] = (__bf16)v.y;
        u.b[2] = (__bf16)v.z; u.b[3] = (__bf16)v.w;
        *(short4*)&xs[row * XS_LD + c4 * 4] = u.s;
    }

    // ---- fused edge gather into xs cols 128..255: wave handles rows w16..w16+15 ----
    {
        const int half = lane >> 5;              // which edge of the pair
        const int c = lane & 31;                 // float4 column
        const int n0r = node0 + (wave << 4);
        int ncl = n0r < N_NODE ? n0r : N_NODE - 1;
        int cnt = count[ncl]; if (cnt > CAP) cnt = CAP;
        int ids = eid[(ncl << 6) + lane];        // full bucket allocated; junk lanes never selected
        for (int i = 0; i < 16; ++i) {
            int cnt_n = 0, ids_n = 0;
            if (i < 15) {                        // prefetch next node's bucket metadata
                int n1 = n0r + i + 1;
                int ncl1 = n1 < N_NODE ? n1 : N_NODE - 1;
                cnt_n = count[ncl1]; if (cnt_n > CAP) cnt_n = CAP;
                ids_n = eid[(ncl1 << 6) + lane];
            }
            float4 acc = {0.f, 0.f, 0.f, 0.f};
            int j = 0;
            for (; j + 8 <= cnt; j += 8) {       // 8 edges: 4 indep 16B loads/lane
                int ea = __shfl(ids, j + half);
                int eb = __shfl(ids, j + 2 + half);
                int ec = __shfl(ids, j + 4 + half);
                int ed = __shfl(ids, j + 6 + half);
                float4 va = ef4[(long)ea * 32 + c];
                float4 vb = ef4[(long)eb * 32 + c];
                float4 vc = ef4[(long)ec * 32 + c];
                float4 vd = ef4[(long)ed * 32 + c];
                acc.x += va.x + vb.x + vc.x + vd.x;
                acc.y += va.y + vb.y + vc.y + vd.y;
                acc.z += va.z + vb.z + vc.z + vd.z;
                acc.w += va.w + vb.w + vc.w + vd.w;
            }
            if (j + 4 <= cnt) {
                int ea = __shfl(ids, j + half);
                int eb = __shfl(ids, j + 2 + half);
                float4 va = ef4[(long)ea * 32 + c];
                float4 vb = ef4[(long)eb * 32 + c];
                acc.x += va.x + vb.x; acc.y += va.y + vb.y;
                acc.z += va.z + vb.z; acc.w += va.w + vb.w;
                j += 4;
            }
            if (j + 2 <= cnt) {
                int e = __shfl(ids, j + half);
                float4 v = ef4[(long)e * 32 + c];
                acc.x += v.x; acc.y += v.y; acc.z += v.z; acc.w += v.w;
                j += 2;
            }
            if (j + half < cnt) {                // last odd edge (half==0 lanes only)
                int e = __shfl(ids, j + half);
                float4 v = ef4[(long)e * 32 + c];
                acc.x += v.x; acc.y += v.y; acc.z += v.z; acc.w += v.w;
            }
            // fold halves: lanes 0..31 hold cols 4c..4c+3 complete
            acc.x += __shfl_xor(acc.x, 32);
            acc.y += __shfl_xor(acc.y, 32);
            acc.z += __shfl_xor(acc.z, 32);
            acc.w += __shfl_xor(acc.w, 32);
            if (half == 0) {
                union { __bf16 b[4]; short4 s; } p;
                p.b[0] = (__bf16)acc.x; p.b[1] = (__bf16)acc.y;
                p.b[2] = (__bf16)acc.z; p.b[3] = (__bf16)acc.w;
                *(short4*)&xs[((wave << 4) + i) * XS_LD + 128 + c * 4] = p.s;
            }
            cnt = cnt_n; ids = ids_n;
        }
    }

    floatx4 acc[8];
    const floatx4 zero = {0.f, 0.f, 0.f, 0.f};

    // A[64 x 32*nk] @ Wpack-tiles -> acc; B-frags from global (L1/L2),
    // 4-wide double buffer to stay under 128 VGPR (4 blocks/CU)
    auto run_gemm = [&](const __bf16* A, int ldA, const uint4* __restrict__ wpt, int nk) {
#pragma unroll
        for (int nt = 0; nt < 8; ++nt) acc[nt] = zero;
        const __bf16* arow = A + (w16 + l16) * ldA + q8;
        bf16x8 a = *(const bf16x8*)arow;
        bf16x8 bA[4], bB[4];
#pragma unroll
        for (int i = 0; i < 4; ++i) bA[i] = as_bf16x8(wpt[i * 64 + lane]);
        for (int kc = 0; kc < nk; ++kc) {
            const uint4* wk = wpt + kc * 512;
            // issue second-half B loads, then MFMA first half
#pragma unroll
            for (int i = 0; i < 4; ++i) bB[i] = as_bf16x8(wk[(4 + i) * 64 + lane]);
            bf16x8 a2 = a;
            if (kc + 1 < nk) a2 = *(const bf16x8*)(arow + (kc + 1) * 32);
#pragma unroll
            for (int nt = 0; nt < 4; ++nt)
                acc[nt] = __builtin_amdgcn_mfma_f32_16x16x32_bf16(a, bA[nt], acc[nt], 0, 0, 0);
            // issue next-kc first-half B loads, then MFMA second half
            if (kc + 1 < nk) {
#pragma unroll
                for (int i = 0; i < 4; ++i) bA[i] = as_bf16x8(wk[512 + i * 64 + lane]);
            }
#pragma unroll
            for (int nt = 0; nt < 4; ++nt)
                acc[4 + nt] = __builtin_amdgcn_mfma_f32_16x16x32_bf16(a, bB[nt], acc[4 + nt], 0, 0, 0);
            a = a2;
        }
    };

    auto epilogue_relu = [&](const float* __restrict__ bias, __bf16* H) {
#pragma unroll
        for (int nt = 0; nt < 8; ++nt) {
            int col = nt * 16 + l16;
            float bv = bias[col];
#pragma unroll
            for (int r = 0; r < 4; ++r) {
                float v = acc[nt][r] + bv;
                v = v > 0.f ? v : 0.f;
                H[(w16 + quad * 4 + r) * H_LD + col] = (__bf16)v;
            }
        }
    };

    __syncthreads();                         // xs staged (nodef + gathered agg)
    run_gemm(xs, XS_LD, wp, 8);              // GEMM1: K = 256
    __syncthreads();                         // all xs reads done (h1 aliases xs)
    epilogue_relu(b1, h1);
    __syncthreads();                         // h1 visible
    run_gemm(h1, H_LD, wp + 4096, 4);        // GEMM2: K = 128
    epilogue_relu(b2, h2);                   // h2 disjoint from h1: no sync needed
    __syncthreads();                         // h2 visible
    run_gemm(h2, H_LD, wp + 6144, 4);        // GEMM3: K = 128

    // ---- final: +b3, LayerNorm, gamma/beta, +residual ----
    float vout[8][4];
    float sum[4] = {0.f, 0.f, 0.f, 0.f};
    float sq[4]  = {0.f, 0.f, 0.f, 0.f};
#pragma unroll
    for (int nt = 0; nt < 8; ++nt) {
        int col = nt * 16 + l16;
        float bv = b3[col];
#pragma unroll
        for (int r = 0; r < 4; ++r) {
            float v = acc[nt][r] + bv;
            vout[nt][r] = v;
            sum[r] += v;
            sq[r] += v * v;
        }
    }
#pragma unroll
    for (int r = 0; r < 4; ++r) {
#pragma unroll
        for (int offs = 1; offs < 16; offs <<= 1) {
            sum[r] += __shfl_xor(sum[r], offs);
            sq[r]  += __shfl_xor(sq[r], offs);
        }
    }
    float mu[4], rs[4];
#pragma unroll
    for (int r = 0; r < 4; ++r) {
        mu[r] = sum[r] * (1.f / 128.f);
        float var = sq[r] * (1.f / 128.f) - mu[r] * mu[r];
        rs[r] = rsqrtf(var + 1e-5f);
    }
#pragma unroll
    for (int nt = 0; nt < 8; ++nt) {
        int col = nt * 16 + l16;
        float g = gamma[col], be = beta[col];
#pragma unroll
        for (int r = 0; r < 4; ++r) {
            int row = w16 + quad * 4 + r;
            int node = node0 + row;
            if (node < N_NODE) {
                long o = (long)node * 128 + col;
                out[o] = (vout[nt][r] - mu[r]) * rs[r] * g + be + nodef[o];
            }
        }
    }
}

extern "C" void kernel_launch(void* const* d_in, const int* in_sizes, int n_in,
                              void* d_out, int out_size, void* d_ws, size_t ws_size,
                              hipStream_t stream)
{
    const float* nodef = (const float*)d_in[0];
    const int*   em    = (const int*)d_in[1];
    const float* ef    = (const float*)d_in[2];
    const float* W1    = (const float*)d_in[3];
    const float* b1    = (const float*)d_in[4];
    const float* W2    = (const float*)d_in[5];
    const float* b2    = (const float*)d_in[6];
    const float* W3    = (const float*)d_in[7];
    const float* b3    = (const float*)d_in[8];
    const float* gamma = (const float*)d_in[9];
    const float* beta  = (const float*)d_in[10];
    float* out = (float*)d_out;

    // workspace layout (ints) — ~13.1 MB total (round-2 footprint, proven safe)
    int* count = (int*)d_ws;                 // 50048
    int* eid   = count + 50048;              // 50000*64 = 3,200,000 (12.8 MB buckets)
    uint4* wp  = (uint4*)(eid + 3200000);    // 8192 uint4 = 128 KB ((50048+3200000)*4 % 16 == 0)

    const int* recv = em + N_EDGE;       // edge_matrix row 1 = receivers

    wrepack_kernel<<<64, 256, 0, stream>>>(W1, W2, W3, wp, count);  // repack + zero count

    int eblocks = (N_EDGE + 255) / 256;  // 2442
    scatter_kernel<<<eblocks, 256, 0, stream>>>(recv, count, eid);

    int mblocks = (N_NODE + MT - 1) / MT;   // 782
    mlp_kernel<<<mblocks, 256, 0, stream>>>(nodef, (const float4*)ef, count, eid,
                                            wp, b1, b2, b3, gamma, beta, out);
}

// Round 4
// 537.879 us; speedup vs baseline: 1.0114x; 1.0114x over previous
//
#include <hip/hip_runtime.h>
#include <hip/hip_bf16.h>

#define N_NODE 50000
#define N_EDGE 625000
#define FDIM 128
#define CAP 64        // bucket capacity per node (max in-degree ~35 for Poisson(12.5))

typedef __bf16 bf16x8 __attribute__((ext_vector_type(8)));
typedef float floatx4 __attribute__((ext_vector_type(4)));

#define MT 64        // nodes per block
#define XS_LD 264    // x-tile row stride (bf16): 256 + 8 pad (row = 528 B, 16B-aligned)
#define H_LD 136     // h row stride (bf16): 128 + 8 pad

__device__ inline bf16x8 as_bf16x8(uint4 v) {
    union { uint4 u; bf16x8 b; } c; c.u = v; return c.b;
}

// ---------------- W repack + count zero (fused) ----------------
// blocks 0..31: Wpack[tile][nt][lane] = uint4 of 8 bf16: W[k0+(lane>>4)*8+j][nt*16+(lane&15)]
//   tiles: 0..7 = W1 (K=256), 8..11 = W2, 12..15 = W3
// blocks 32..63: zero count[]
__global__ __launch_bounds__(256) void wrepack_kernel(
    const float* __restrict__ W1, const float* __restrict__ W2,
    const float* __restrict__ W3, uint4* __restrict__ wp,
    int* __restrict__ count)
{
    if (blockIdx.x >= 32) {
        int idx = (blockIdx.x - 32) * 256 + threadIdx.x;
        for (int i = idx; i < N_NODE; i += 32 * 256) count[i] = 0;
        return;
    }
    int g = blockIdx.x * 256 + threadIdx.x;   // 0..8191
    int lane = g & 63;
    int nt = (g >> 6) & 7;
    int tile = g >> 9;
    const float* W; int k0;
    if (tile < 8)       { W = W1; k0 = tile * 32; }
    else if (tile < 12) { W = W2; k0 = (tile - 8) * 32; }
    else                { W = W3; k0 = (tile - 12) * 32; }
    int n = nt * 16 + (lane & 15);
    int kb = k0 + (lane >> 4) * 8;
    union { __bf16 b[8]; uint4 u; } p;
#pragma unroll
    for (int j = 0; j < 8; ++j) p.b[j] = (__bf16)W[(kb + j) * 128 + n];
    wp[g] = p.u;
}

// ---------------- bucket scatter: 4 edges/thread, int4 recv read ----------------
__global__ __launch_bounds__(256) void scatter_kernel(
    const int4* __restrict__ recv4, int* __restrict__ count, int* __restrict__ eid)
{
    int tid = blockIdx.x * 256 + threadIdx.x;
    if (tid < N_EDGE / 4) {                      // 625000 % 4 == 0, exact
        int4 r = recv4[tid];
        int e0 = tid * 4;
        int p0 = atomicAdd(&count[r.x], 1);      // 4 independent atomics in flight
        int p1 = atomicAdd(&count[r.y], 1);
        int p2 = atomicAdd(&count[r.z], 1);
        int p3 = atomicAdd(&count[r.w], 1);
        if (p0 < CAP) eid[(r.x << 6) + p0] = e0;
        if (p1 < CAP) eid[(r.y << 6) + p1] = e0 + 1;
        if (p2 < CAP) eid[(r.z << 6) + p2] = e0 + 2;
        if (p3 < CAP) eid[(r.w << 6) + p3] = e0 + 3;
    }
}

// ---------------- edge gather: one wave per node, single pass (cnt <= 64) ----------------
__global__ __launch_bounds__(256) void gather_kernel(
    const float4* __restrict__ ef4, const int* __restrict__ count,
    const int* __restrict__ eid, uint2* __restrict__ agg)
{
    int wave = threadIdx.x >> 6;
    int lane = threadIdx.x & 63;
    int node = blockIdx.x * 4 + wave;                // grid = 12500, exact
    int half = lane >> 5;                            // which edge of the pair
    int c = lane & 31;                               // float4 column
    float4 acc = {0.f, 0.f, 0.f, 0.f};
    // ids load is UNCONDITIONAL: independent of cnt -> both HBM loads in flight
    // together (bucket fully allocated; junk lanes never selected by shuffles)
    int ids = eid[(node << 6) + lane];
    int cnt = count[node]; if (cnt > CAP) cnt = CAP;
    int j = 0;
    for (; j + 8 <= cnt; j += 8) {                   // 8 edges: 4 indep 16B loads/lane
        int ea = __shfl(ids, j + half);
        int eb = __shfl(ids, j + 2 + half);
        int ec = __shfl(ids, j + 4 + half);
        int ed = __shfl(ids, j + 6 + half);
        float4 va = ef4[(long)ea * 32 + c];
        float4 vb = ef4[(long)eb * 32 + c];
        float4 vc = ef4[(long)ec * 32 + c];
        float4 vd = ef4[(long)ed * 32 + c];
        acc.x += va.x + vb.x + vc.x + vd.x;
        acc.y += va.y + vb.y + vc.y + vd.y;
        acc.z += va.z + vb.z + vc.z + vd.z;
        acc.w += va.w + vb.w + vc.w + vd.w;
    }
    if (j + 4 <= cnt) {                              // 4 edges: 2 loads/lane
        int ea = __shfl(ids, j + half);
        int eb = __shfl(ids, j + 2 + half);
        float4 va = ef4[(long)ea * 32 + c];
        float4 vb = ef4[(long)eb * 32 + c];
        acc.x += va.x + vb.x; acc.y += va.y + vb.y;
        acc.z += va.z + vb.z; acc.w += va.w + vb.w;
        j += 4;
    }
    if (j + 2 <= cnt) {                              // 2 edges: 1 load/lane
        int e = __shfl(ids, j + half);
        float4 v = ef4[(long)e * 32 + c];
        acc.x += v.x; acc.y += v.y; acc.z += v.z; acc.w += v.w;
        j += 2;
    }
    if (j + half < cnt) {                            // last odd edge (half==0 lanes only)
        int e = __shfl(ids, j + half);
        float4 v = ef4[(long)e * 32 + c];
        acc.x += v.x; acc.y += v.y; acc.z += v.z; acc.w += v.w;
    }
    // fold the two halves: lanes 0..31 get cols 4c..4c+3 complete
    acc.x += __shfl_xor(acc.x, 32);
    acc.y += __shfl_xor(acc.y, 32);
    acc.z += __shfl_xor(acc.z, 32);
    acc.w += __shfl_xor(acc.w, 32);
    if (half == 0) {
        union { __bf16 b[4]; uint2 u; } p;
        p.b[0] = (__bf16)acc.x; p.b[1] = (__bf16)acc.y;
        p.b[2] = (__bf16)acc.z; p.b[3] = (__bf16)acc.w;
        agg[(long)node * 32 + c] = p.u;              // 256 B coalesced row
    }
}

// ------------- MLP + LayerNorm + residual -------------
// LDS plan (34944 B -> 4 blocks/CU):
//   xs = smem[0..16896)           x-tile, alive through GEMM1
//   h1 = smem[0..8704)            written after sync (xs dead), read by GEMM2
//   h2 = smem[8704..17408)        disjoint from h1; written by epi2, read by GEMM3
__global__ __launch_bounds__(256, 4) void mlp_kernel(
    const float* __restrict__ nodef, const int* __restrict__ agg32,
    const uint4* __restrict__ wp,
    const float* __restrict__ b1, const float* __restrict__ b2,
    const float* __restrict__ b3,
    const float* __restrict__ gamma, const float* __restrict__ beta,
    float* __restrict__ out)
{
    __shared__ __bf16 smem[17472];
    __bf16* xs = smem;
    __bf16* h1 = smem;
    __bf16* h2 = smem + 8704;

    const int t = threadIdx.x;
    const int wave = t >> 6;
    const int lane = t & 63;
    const int quad = lane >> 4;
    const int l16 = lane & 15;
    const int w16 = wave << 4;
    const int q8 = quad << 3;
    const int node0 = blockIdx.x * MT;

    // ---- stage x-tile ----
    const float4* nf4 = (const float4*)nodef;
#pragma unroll
    for (int i = 0; i < 8; ++i) {
        int it = i * 256 + t;
        int row = it >> 5;
        int c4 = it & 31;
        int node = node0 + row;
        if (node >= N_NODE) node = N_NODE - 1;   // junk ok; masked at store
        float4 v = nf4[(long)node * 32 + c4];
        union { __bf16 b[4]; short4 s; } u;
        u.b[0] = (__bf16)v.x; u.b[1] = (__bf16)v.y;
        u.b[2] = (__bf16)v.z; u.b[3] = (__bf16)v.w;
        *(short4*)&xs[row * XS_LD + c4 * 4] = u.s;
    }
    const int4* ag4 = (const int4*)agg32;        // 16 int4 per agg row
#pragma unroll
    for (int i = 0; i < 4; ++i) {
        int it = i * 256 + t;
        int row = it >> 4;
        int c8 = it & 15;
        int node = node0 + row;
        if (node >= N_NODE) node = N_NODE - 1;
        int4 v = ag4[(long)node * 16 + c8];
        *(int4*)&xs[row * XS_LD + 128 + c8 * 8] = v;
    }

    floatx4 acc[8];
    const floatx4 zero = {0.f, 0.f, 0.f, 0.f};

    // A[64 x 32*nk] @ Wpack-tiles -> acc; B-frags from global (L1/L2),
    // 4-wide double buffer to stay under 128 VGPR (4 blocks/CU)
    auto run_gemm = [&](const __bf16* A, int ldA, const uint4* __restrict__ wpt, int nk) {
#pragma unroll
        for (int nt = 0; nt < 8; ++nt) acc[nt] = zero;
        const __bf16* arow = A + (w16 + l16) * ldA + q8;
        bf16x8 a = *(const bf16x8*)arow;
        bf16x8 bA[4], bB[4];
#pragma unroll
        for (int i = 0; i < 4; ++i) bA[i] = as_bf16x8(wpt[i * 64 + lane]);
        for (int kc = 0; kc < nk; ++kc) {
            const uint4* wk = wpt + kc * 512;
            // issue second-half B loads, then MFMA first half
#pragma unroll
            for (int i = 0; i < 4; ++i) bB[i] = as_bf16x8(wk[(4 + i) * 64 + lane]);
            bf16x8 a2 = a;
            if (kc + 1 < nk) a2 = *(const bf16x8*)(arow + (kc + 1) * 32);
#pragma unroll
            for (int nt = 0; nt < 4; ++nt)
                acc[nt] = __builtin_amdgcn_mfma_f32_16x16x32_bf16(a, bA[nt], acc[nt], 0, 0, 0);
            // issue next-kc first-half B loads, then MFMA second half
            if (kc + 1 < nk) {
#pragma unroll
                for (int i = 0; i < 4; ++i) bA[i] = as_bf16x8(wk[512 + i * 64 + lane]);
            }
#pragma unroll
            for (int nt = 0; nt < 4; ++nt)
                acc[4 + nt] = __builtin_amdgcn_mfma_f32_16x16x32_bf16(a, bB[nt], acc[4 + nt], 0, 0, 0);
            a = a2;
        }
    };

    auto epilogue_relu = [&](const float* __restrict__ bias, __bf16* H) {
#pragma unroll
        for (int nt = 0; nt < 8; ++nt) {
            int col = nt * 16 + l16;
            float bv = bias[col];
#pragma unroll
            for (int r = 0; r < 4; ++r) {
                float v = acc[nt][r] + bv;
                v = v > 0.f ? v : 0.f;
                H[(w16 + quad * 4 + r) * H_LD + col] = (__bf16)v;
            }
        }
    };

    __syncthreads();                         // xs staged
    run_gemm(xs, XS_LD, wp, 8);              // GEMM1: K = 256
    __syncthreads();                         // all xs reads done (h1 aliases xs)
    epilogue_relu(b1, h1);
    __syncthreads();                         // h1 visible
    run_gemm(h1, H_LD, wp + 4096, 4);        // GEMM2: K = 128
    epilogue_relu(b2, h2);                   // h2 disjoint from h1: no sync needed
    __syncthreads();                         // h2 visible
    run_gemm(h2, H_LD, wp + 6144, 4);        // GEMM3: K = 128

    // ---- final: +b3, LayerNorm, gamma/beta, +residual ----
    float vout[8][4];
    float sum[4] = {0.f, 0.f, 0.f, 0.f};
    float sq[4]  = {0.f, 0.f, 0.f, 0.f};
#pragma unroll
    for (int nt = 0; nt < 8; ++nt) {
        int col = nt * 16 + l16;
        float bv = b3[col];
#pragma unroll
        for (int r = 0; r < 4; ++r) {
            float v = acc[nt][r] + bv;
            vout[nt][r] = v;
            sum[r] += v;
            sq[r] += v * v;
        }
    }
#pragma unroll
    for (int r = 0; r < 4; ++r) {
#pragma unroll
        for (int offs = 1; offs < 16; offs <<= 1) {
            sum[r] += __shfl_xor(sum[r], offs);
            sq[r]  += __shfl_xor(sq[r], offs);
        }
    }
    float mu[4], rs[4];
#pragma unroll
    for (int r = 0; r < 4; ++r) {
        mu[r] = sum[r] * (1.f / 128.f);
        float var = sq[r] * (1.f / 128.f) - mu[r] * mu[r];
        rs[r] = rsqrtf(var + 1e-5f);
    }
#pragma unroll
    for (int nt = 0; nt < 8; ++nt) {
        int col = nt * 16 + l16;
        float g = gamma[col], be = beta[col];
#pragma unroll
        for (int r = 0; r < 4; ++r) {
            int row = w16 + quad * 4 + r;
            int node = node0 + row;
            if (node < N_NODE) {
                long o = (long)node * 128 + col;
                out[o] = (vout[nt][r] - mu[r]) * rs[r] * g + be + nodef[o];
            }
        }
    }
}

extern "C" void kernel_launch(void* const* d_in, const int* in_sizes, int n_in,
                              void* d_out, int out_size, void* d_ws, size_t ws_size,
                              hipStream_t stream)
{
    const float* nodef = (const float*)d_in[0];
    const int*   em    = (const int*)d_in[1];
    const float* ef    = (const float*)d_in[2];
    const float* W1    = (const float*)d_in[3];
    const float* b1    = (const float*)d_in[4];
    const float* W2    = (const float*)d_in[5];
    const float* b2    = (const float*)d_in[6];
    const float* W3    = (const float*)d_in[7];
    const float* b3    = (const float*)d_in[8];
    const float* gamma = (const float*)d_in[9];
    const float* beta  = (const float*)d_in[10];
    float* out = (float*)d_out;

    // workspace layout (ints) — ~13.1 MB total (round-2 footprint, proven safe)
    int* count = (int*)d_ws;                 // 50048
    int* agg32 = count + 50048;              // 50000*64 ints (bf16x2) = 12.8 MB
    uint4* wp  = (uint4*)(agg32 + 3200000);  // 8192 uint4 = 128 KB (offset 16B-aligned)

    // eid buckets (12.8 MB) live in d_out (25.6 MB): scratch until mlp_kernel,
    // which is stream-ordered after gather and fully overwrites out.
    int* eid = (int*)d_out;

    const int* recv = em + N_EDGE;       // edge_matrix row 1 = receivers
    // recv byte offset = 625000*4 = 2.5e6, divisible by 16 -> int4 loads aligned

    wrepack_kernel<<<64, 256, 0, stream>>>(W1, W2, W3, wp, count);  // repack + zero count

    int sblocks = (N_EDGE / 4 + 255) / 256;  // 611
    scatter_kernel<<<sblocks, 256, 0, stream>>>((const int4*)recv, count, eid);
    gather_kernel<<<N_NODE / 4, 256, 0, stream>>>((const float4*)ef, count, eid, (uint2*)agg32);

    int mblocks = (N_NODE + MT - 1) / MT;   // 782
    mlp_kernel<<<mblocks, 256, 0, stream>>>(nodef, agg32, wp, b1, b2, b3,
                                            gamma, beta, out);
}

// Round 5
// 527.419 us; speedup vs baseline: 1.0314x; 1.0198x over previous
//
#include <hip/hip_runtime.h>
#include <hip/hip_bf16.h>

#define N_NODE 50000
#define N_EDGE 625000
#define FDIM 128
#define CAP 64        // bucket capacity per node (max in-degree ~35 for Poisson(12.5))

typedef __bf16 bf16x8 __attribute__((ext_vector_type(8)));
typedef float floatx4 __attribute__((ext_vector_type(4)));

#define MT 32        // nodes per block (2 row-tiles x 2 column-half waves)
#define XS_LD 264    // x-tile row stride (bf16): 256 + 8 pad (row = 528 B, 16B-aligned)
#define H_LD 136     // h row stride (bf16): 128 + 8 pad

__device__ inline bf16x8 as_bf16x8(uint4 v) {
    union { uint4 u; bf16x8 b; } c; c.u = v; return c.b;
}

// ---------------- W repack + count zero (fused) ----------------
// blocks 0..31: Wpack[tile][nt][lane] = uint4 of 8 bf16: W[k0+(lane>>4)*8+j][nt*16+(lane&15)]
//   tiles: 0..7 = W1 (K=256), 8..11 = W2, 12..15 = W3
// blocks 32..63: zero count[]
__global__ __launch_bounds__(256) void wrepack_kernel(
    const float* __restrict__ W1, const float* __restrict__ W2,
    const float* __restrict__ W3, uint4* __restrict__ wp,
    int* __restrict__ count)
{
    if (blockIdx.x >= 32) {
        int idx = (blockIdx.x - 32) * 256 + threadIdx.x;
        for (int i = idx; i < N_NODE; i += 32 * 256) count[i] = 0;
        return;
    }
    int g = blockIdx.x * 256 + threadIdx.x;   // 0..8191
    int lane = g & 63;
    int nt = (g >> 6) & 7;
    int tile = g >> 9;
    const float* W; int k0;
    if (tile < 8)       { W = W1; k0 = tile * 32; }
    else if (tile < 12) { W = W2; k0 = (tile - 8) * 32; }
    else                { W = W3; k0 = (tile - 12) * 32; }
    int n = nt * 16 + (lane & 15);
    int kb = k0 + (lane >> 4) * 8;
    union { __bf16 b[8]; uint4 u; } p;
#pragma unroll
    for (int j = 0; j < 8; ++j) p.b[j] = (__bf16)W[(kb + j) * 128 + n];
    wp[g] = p.u;
}

// ---------------- bucket scatter: 4 edges/thread, int4 recv read ----------------
__global__ __launch_bounds__(256) void scatter_kernel(
    const int4* __restrict__ recv4, int* __restrict__ count, int* __restrict__ eid)
{
    int tid = blockIdx.x * 256 + threadIdx.x;
    if (tid < N_EDGE / 4) {                      // 625000 % 4 == 0, exact
        int4 r = recv4[tid];
        int e0 = tid * 4;
        int p0 = atomicAdd(&count[r.x], 1);      // 4 independent atomics in flight
        int p1 = atomicAdd(&count[r.y], 1);
        int p2 = atomicAdd(&count[r.z], 1);
        int p3 = atomicAdd(&count[r.w], 1);
        if (p0 < CAP) eid[(r.x << 6) + p0] = e0;
        if (p1 < CAP) eid[(r.y << 6) + p1] = e0 + 1;
        if (p2 < CAP) eid[(r.z << 6) + p2] = e0 + 2;
        if (p3 < CAP) eid[(r.w << 6) + p3] = e0 + 3;
    }
}

// ---------------- edge gather: one wave per node, single pass (cnt <= 64) ----------------
__global__ __launch_bounds__(256) void gather_kernel(
    const float4* __restrict__ ef4, const int* __restrict__ count,
    const int* __restrict__ eid, uint2* __restrict__ agg)
{
    int wave = threadIdx.x >> 6;
    int lane = threadIdx.x & 63;
    int node = blockIdx.x * 4 + wave;                // grid = 12500, exact
    int half = lane >> 5;                            // which edge of the pair
    int c = lane & 31;                               // float4 column
    float4 acc = {0.f, 0.f, 0.f, 0.f};
    // ids load unconditional: independent of cnt, both HBM loads in flight together
    int ids = eid[(node << 6) + lane];
    int cnt = count[node]; if (cnt > CAP) cnt = CAP;
    int j = 0;
    for (; j + 8 <= cnt; j += 8) {                   // 8 edges: 4 indep 16B loads/lane
        int ea = __shfl(ids, j + half);
        int eb = __shfl(ids, j + 2 + half);
        int ec = __shfl(ids, j + 4 + half);
        int ed = __shfl(ids, j + 6 + half);
        float4 va = ef4[(long)ea * 32 + c];
        float4 vb = ef4[(long)eb * 32 + c];
        float4 vc = ef4[(long)ec * 32 + c];
        float4 vd = ef4[(long)ed * 32 + c];
        acc.x += va.x + vb.x + vc.x + vd.x;
        acc.y += va.y + vb.y + vc.y + vd.y;
        acc.z += va.z + vb.z + vc.z + vd.z;
        acc.w += va.w + vb.w + vc.w + vd.w;
    }
    if (j + 4 <= cnt) {                              // 4 edges: 2 loads/lane
        int ea = __shfl(ids, j + half);
        int eb = __shfl(ids, j + 2 + half);
        float4 va = ef4[(long)ea * 32 + c];
        float4 vb = ef4[(long)eb * 32 + c];
        acc.x += va.x + vb.x; acc.y += va.y + vb.y;
        acc.z += va.z + vb.z; acc.w += va.w + vb.w;
        j += 4;
    }
    if (j + 2 <= cnt) {                              // 2 edges: 1 load/lane
        int e = __shfl(ids, j + half);
        float4 v = ef4[(long)e * 32 + c];
        acc.x += v.x; acc.y += v.y; acc.z += v.z; acc.w += v.w;
        j += 2;
    }
    if (j + half < cnt) {                            // last odd edge (half==0 lanes only)
        int e = __shfl(ids, j + half);
        float4 v = ef4[(long)e * 32 + c];
        acc.x += v.x; acc.y += v.y; acc.z += v.z; acc.w += v.w;
    }
    // fold the two halves: lanes 0..31 get cols 4c..4c+3 complete
    acc.x += __shfl_xor(acc.x, 32);
    acc.y += __shfl_xor(acc.y, 32);
    acc.z += __shfl_xor(acc.z, 32);
    acc.w += __shfl_xor(acc.w, 32);
    if (half == 0) {
        union { __bf16 b[4]; uint2 u; } p;
        p.b[0] = (__bf16)acc.x; p.b[1] = (__bf16)acc.y;
        p.b[2] = (__bf16)acc.z; p.b[3] = (__bf16)acc.w;
        agg[(long)node * 32 + c] = p.u;              // 256 B coalesced row
    }
}

// ------------- MLP + LayerNorm + residual (nt-split: 2x waves) -------------
// MT=32, 4 waves: wave = (row-tile = wave>>1, column-half = wave&1).
// Each wave: 16 rows x 64 cols, acc[4] floatx4, 4 B-frags/kc -> VGPR ~80-100,
// grid 1563 x 4 waves = 6252 waves -> 20-24 waves/CU (was 12).
// LDS (~17.9 KB -> >=5 blocks/CU):
//   xs = smem[0..8448)   x-tile, alive through GEMM1
//   h1 = smem[0..4352)   written after sync (xs dead), read by GEMM2
//   h2 = smem[4352..8704) disjoint from h1
//   red[2][32][2]        cross-half LayerNorm partials
__global__ __launch_bounds__(256, 5) void mlp_kernel(
    const float* __restrict__ nodef, const int* __restrict__ agg32,
    const uint4* __restrict__ wp,
    const float* __restrict__ b1, const float* __restrict__ b2,
    const float* __restrict__ b3,
    const float* __restrict__ gamma, const float* __restrict__ beta,
    float* __restrict__ out)
{
    __shared__ __bf16 smem[8704];
    __shared__ float red[2][32][2];
    __bf16* xs = smem;
    __bf16* h1 = smem;
    __bf16* h2 = smem + 4352;

    const int t = threadIdx.x;
    const int wave = t >> 6;
    const int lane = t & 63;
    const int quad = lane >> 4;
    const int l16 = lane & 15;
    const int tile = wave >> 1;          // row tile 0..1
    const int ch   = wave & 1;           // column half 0..1
    const int trow = tile << 4;
    const int q8 = quad << 3;
    const int node0 = blockIdx.x * MT;

    // ---- stage x-tile: nodef cols 0..127 (32 rows x 32 float4, 4 iters) ----
    const float4* nf4 = (const float4*)nodef;
#pragma unroll
    for (int i = 0; i < 4; ++i) {
        int it = i * 256 + t;
        int row = it >> 5;
        int c4 = it & 31;
        int node = node0 + row;
        if (node >= N_NODE) node = N_NODE - 1;   // junk ok; masked at store
        float4 v = nf4[(long)node * 32 + c4];
        union { __bf16 b[4]; short4 s; } u;
        u.b[0] = (__bf16)v.x; u.b[1] = (__bf16)v.y;
        u.b[2] = (__bf16)v.z; u.b[3] = (__bf16)v.w;
        *(short4*)&xs[row * XS_LD + c4 * 4] = u.s;
    }
    // ---- stage agg cols 128..255 (32 rows x 16 int4, 2 iters) ----
    const int4* ag4 = (const int4*)agg32;
#pragma unroll
    for (int i = 0; i < 2; ++i) {
        int it = i * 256 + t;
        int row = it >> 4;
        int c8 = it & 15;
        int node = node0 + row;
        if (node >= N_NODE) node = N_NODE - 1;
        int4 v = ag4[(long)node * 16 + c8];
        *(int4*)&xs[row * XS_LD + 128 + c8 * 8] = v;
    }

    floatx4 acc[4];
    const floatx4 zero = {0.f, 0.f, 0.f, 0.f};

    // A[16 x 32*nk] @ Wpack half-tiles -> acc[4]; B-frags from global (L1/L2),
    // full-kc double buffer (4+4 frags)
    auto run_gemm = [&](const __bf16* A, int ldA, const uint4* __restrict__ wpt, int nk) {
#pragma unroll
        for (int nt = 0; nt < 4; ++nt) acc[nt] = zero;
        const __bf16* arow = A + (trow + l16) * ldA + q8;
        const uint4* wc = wpt + (ch << 2) * 64;      // this wave's column half
        bf16x8 a = *(const bf16x8*)arow;
        bf16x8 bA[4], bB[4];
#pragma unroll
        for (int i = 0; i < 4; ++i) bA[i] = as_bf16x8(wc[i * 64 + lane]);
        for (int kc = 0; kc < nk; ++kc) {
            bf16x8 a2 = a;
            if (kc + 1 < nk) {                       // prefetch next kc
                const uint4* wn = wc + (kc + 1) * 512;
#pragma unroll
                for (int i = 0; i < 4; ++i) bB[i] = as_bf16x8(wn[i * 64 + lane]);
                a2 = *(const bf16x8*)(arow + (kc + 1) * 32);
            }
#pragma unroll
            for (int nt = 0; nt < 4; ++nt)
                acc[nt] = __builtin_amdgcn_mfma_f32_16x16x32_bf16(a, bA[nt], acc[nt], 0, 0, 0);
            a = a2;
#pragma unroll
            for (int i = 0; i < 4; ++i) bA[i] = bB[i];
        }
    };

    auto epilogue_relu = [&](const float* __restrict__ bias, __bf16* H) {
#pragma unroll
        for (int nt = 0; nt < 4; ++nt) {
            int col = (ch << 6) + nt * 16 + l16;
            float bv = bias[col];
#pragma unroll
            for (int r = 0; r < 4; ++r) {
                float v = acc[nt][r] + bv;
                v = v > 0.f ? v : 0.f;
                H[(trow + quad * 4 + r) * H_LD + col] = (__bf16)v;
            }
        }
    };

    __syncthreads();                         // xs staged
    run_gemm(xs, XS_LD, wp, 8);              // GEMM1: K = 256
    __syncthreads();                         // all xs reads done (h1 aliases xs)
    epilogue_relu(b1, h1);
    __syncthreads();                         // h1 visible
    run_gemm(h1, H_LD, wp + 4096, 4);        // GEMM2: K = 128
    epilogue_relu(b2, h2);                   // h2 disjoint from h1: no sync needed
    __syncthreads();                         // h2 visible
    run_gemm(h2, H_LD, wp + 6144, 4);        // GEMM3: K = 128

    // ---- final: +b3, LayerNorm (cross-half via LDS), gamma/beta, +residual ----
    float vout[4][4];
    float sum[4] = {0.f, 0.f, 0.f, 0.f};
    float sq[4]  = {0.f, 0.f, 0.f, 0.f};
#pragma unroll
    for (int nt = 0; nt < 4; ++nt) {
        int col = (ch << 6) + nt * 16 + l16;
        float bv = b3[col];
#pragma unroll
        for (int r = 0; r < 4; ++r) {
            float v = acc[nt][r] + bv;
            vout[nt][r] = v;
            sum[r] += v;
            sq[r] += v * v;
        }
    }
#pragma unroll
    for (int r = 0; r < 4; ++r) {
#pragma unroll
        for (int offs = 1; offs < 16; offs <<= 1) {
            sum[r] += __shfl_xor(sum[r], offs);
            sq[r]  += __shfl_xor(sq[r], offs);
        }
    }
    if (l16 == 0) {
#pragma unroll
        for (int r = 0; r < 4; ++r) {
            red[ch][trow + quad * 4 + r][0] = sum[r];
            red[ch][trow + quad * 4 + r][1] = sq[r];
        }
    }
    __syncthreads();
    float mu[4], rs[4];
#pragma unroll
    for (int r = 0; r < 4; ++r) {
        int row = trow + quad * 4 + r;
        float s = red[0][row][0] + red[1][row][0];
        float q = red[0][row][1] + red[1][row][1];
        mu[r] = s * (1.f / 128.f);
        float var = q * (1.f / 128.f) - mu[r] * mu[r];
        rs[r] = rsqrtf(var + 1e-5f);
    }
#pragma unroll
    for (int nt = 0; nt < 4; ++nt) {
        int col = (ch << 6) + nt * 16 + l16;
        float g = gamma[col], be = beta[col];
#pragma unroll
        for (int r = 0; r < 4; ++r) {
            int row = trow + quad * 4 + r;
            int node = node0 + row;
            if (node < N_NODE) {
                long o = (long)node * 128 + col;
                out[o] = (vout[nt][r] - mu[r]) * rs[r] * g + be + nodef[o];
            }
        }
    }
}

extern "C" void kernel_launch(void* const* d_in, const int* in_sizes, int n_in,
                              void* d_out, int out_size, void* d_ws, size_t ws_size,
                              hipStream_t stream)
{
    const float* nodef = (const float*)d_in[0];
    const int*   em    = (const int*)d_in[1];
    const float* ef    = (const float*)d_in[2];
    const float* W1    = (const float*)d_in[3];
    const float* b1    = (const float*)d_in[4];
    const float* W2    = (const float*)d_in[5];
    const float* b2    = (const float*)d_in[6];
    const float* W3    = (const float*)d_in[7];
    const float* b3    = (const float*)d_in[8];
    const float* gamma = (const float*)d_in[9];
    const float* beta  = (const float*)d_in[10];
    float* out = (float*)d_out;

    // workspace layout (ints) — ~13.1 MB total (proven safe)
    int* count = (int*)d_ws;                 // 50048
    int* agg32 = count + 50048;              // 50000*64 ints (bf16x2) = 12.8 MB
    uint4* wp  = (uint4*)(agg32 + 3200000);  // 8192 uint4 = 128 KB (offset 16B-aligned)

    // eid buckets (12.8 MB) live in d_out (25.6 MB): scratch until mlp_kernel,
    // which is stream-ordered after gather and fully overwrites out.
    int* eid = (int*)d_out;

    const int* recv = em + N_EDGE;       // edge_matrix row 1 = receivers
    // recv byte offset = 625000*4 = 2.5e6, divisible by 16 -> int4 loads aligned

    wrepack_kernel<<<64, 256, 0, stream>>>(W1, W2, W3, wp, count);  // repack + zero count

    int sblocks = (N_EDGE / 4 + 255) / 256;  // 611
    scatter_kernel<<<sblocks, 256, 0, stream>>>((const int4*)recv, count, eid);
    gather_kernel<<<N_NODE / 4, 256, 0, stream>>>((const float4*)ef, count, eid, (uint2*)agg32);

    int mblocks = (N_NODE + MT - 1) / MT;   // 1563
    mlp_kernel<<<mblocks, 256, 0, stream>>>(nodef, agg32, wp, b1, b2, b3,
                                            gamma, beta, out);
}